// Round 3
// baseline (636.341 us; speedup 1.0000x reference)
//
#include <hip/hip_runtime.h>
#include <hip/hip_fp16.h>
#include <cmath>

#define NLVL 16
#define TSIZE (1u << 19)
#define HMASK ((1u << 19) - 1u)
#define PRIME1 2654435761u
#define FSCALE 1024.0f          // 2^10: keeps |v|<=1e-4 in fp16-normal range
#define FINV   (1.0f/1024.0f)   // exact power of 2 -> no extra rounding
#define NBUCK_1D 128
#define NBUCK (NBUCK_1D * NBUCK_1D)   // 16384 buckets, ~61 pts each (~1 wave)

typedef float f32x4 __attribute__((ext_vector_type(4)));
typedef unsigned int       u32;
typedef unsigned long long u64;

struct Params {
    float rf[NLVL];
    int   ri[NLVL];
    int   base[NLVL];     // u32 index of level's dense table inside ws
    int   stride[NLVL];   // ri+2 (one pad cell per row so the 8B load at cx=ri is in-bounds)
};

__device__ __forceinline__ float2 h2f(u32 u) {
    __half2 h; __builtin_memcpy(&h, &u, 4);
    return __half22float2(h);
}

__device__ __forceinline__ int bucket_of(float2 xy) {
    int bx = min(NBUCK_1D - 1, max(0, (int)(xy.x * (float)NBUCK_1D)));
    int by = min(NBUCK_1D - 1, max(0, (int)(xy.y * (float)NBUCK_1D)));
    return by * NBUCK_1D + bx;
}

// Pre-pass: un-hash each level's window [0,res]^2 into a dense, L2-resident
// half2 table (scaled by 2^10). 714K cells -> 2.86 MiB (fits 4 MiB/XCD L2).
// Note: (cx ^ (cy*PRIME1)) & MASK == (cy*PRIME1 & MASK) ^ cx for cx<2^19,
// so a wave's 64 reads cover one lane-permuted contiguous 512B window: coalesced.
__global__ __launch_bounds__(256) void build_dense_h(
    const float2* __restrict__ emb, u32* __restrict__ dense, Params p)
{
    const int l  = blockIdx.y;
    const int cy = blockIdx.x;
    const int ri = p.ri[l];
    if (cy > ri) return;
    const unsigned hy = (unsigned)cy * PRIME1;
    const u64* tab = (const u64*)(emb + (size_t)l * TSIZE);
    u32* drow = dense + p.base[l] + (size_t)cy * p.stride[l];
    for (int cx = threadIdx.x; cx <= ri; cx += 256) {
        u64 raw = __builtin_nontemporal_load(tab + (((unsigned)cx ^ hy) & HMASK));
        float2 v; __builtin_memcpy(&v, &raw, 8);
        const u32 h0 = (u32)__half_as_ushort(__float2half_rn(v.x * FSCALE));
        const u32 h1 = (u32)__half_as_ushort(__float2half_rn(v.y * FSCALE));
        drow[cx] = h0 | (h1 << 16);
    }
}

// Sort pass 1: bucket histogram (counts must be zeroed before launch).
__global__ __launch_bounds__(256) void hist_k(
    const float2* __restrict__ x, u32* __restrict__ counts, int n)
{
    const int i = blockIdx.x * 256 + threadIdx.x;
    if (i >= n) return;
    u64 raw = __builtin_nontemporal_load((const u64*)(x + i));
    float2 xy; __builtin_memcpy(&xy, &raw, 8);
    atomicAdd(&counts[bucket_of(xy)], 1u);
}

// Sort pass 2: exclusive prefix sum of 16384 counts, single 1024-thread block.
__global__ __launch_bounds__(1024) void scan16k(
    const u32* __restrict__ counts, u32* __restrict__ offs, u32* __restrict__ cursor)
{
    __shared__ u32 wsum[16];
    const int t = threadIdx.x;          // 0..1023, 16 counts each
    u32 v[16]; u32 s = 0;
    #pragma unroll
    for (int k = 0; k < 16; ++k) { v[k] = counts[t * 16 + k]; s += v[k]; }
    u32 inc = s;                        // wave-inclusive scan of thread sums
    #pragma unroll
    for (int d = 1; d < 64; d <<= 1) {
        u32 tt = __shfl_up(inc, d);
        if ((t & 63) >= d) inc += tt;
    }
    if ((t & 63) == 63) wsum[t >> 6] = inc;
    __syncthreads();
    if (t < 16) {                       // wave 0 scans the 16 wave sums
        u32 w = wsum[t];
        u32 wi = w;
        #pragma unroll
        for (int d = 1; d < 16; d <<= 1) {
            u32 tt = __shfl_up(wi, d);
            if (t >= d) wi += tt;
        }
        wsum[t] = wi - w;               // exclusive
    }
    __syncthreads();
    u32 run = wsum[t >> 6] + (inc - s); // this thread's exclusive prefix
    #pragma unroll
    for (int k = 0; k < 16; ++k) {
        offs[t * 16 + k]   = run;
        cursor[t * 16 + k] = run;
        run += v[k];
    }
}

// Sort pass 3: scatter points into bucket-sorted order (writes cluster per
// bucket -> L2 merges them into full lines).
__global__ __launch_bounds__(256) void scatter_k(
    const float2* __restrict__ x, u32* __restrict__ cursor,
    float2* __restrict__ sx, u32* __restrict__ oidx, int n)
{
    const int i = blockIdx.x * 256 + threadIdx.x;
    if (i >= n) return;
    u64 raw = __builtin_nontemporal_load((const u64*)(x + i));
    float2 xy; __builtin_memcpy(&xy, &raw, 8);
    const u32 pos = atomicAdd(&cursor[bucket_of(xy)], 1u);
    sx[pos] = xy;
    oidx[pos] = (u32)i;
}

// Main (sorted): a wave's 64 points sit in ~one 1/128-square -> each level's
// row-gathers touch ~5-10 L2 lines instead of 64. Each thread owns its point's
// full 32-float output -> direct per-thread 128B nt stores, zero LDS.
__global__ __launch_bounds__(256) void hash_embed_sorted(
    const float2* __restrict__ sx,
    const u32*    __restrict__ oidx,
    const u32*    __restrict__ dense,
    float*        __restrict__ out,
    Params p, int n)
{
    const int i = blockIdx.x * 256 + threadIdx.x;
    if (i >= n) return;
    u64 raw = __builtin_nontemporal_load((const u64*)(sx + i));
    float2 xy; __builtin_memcpy(&xy, &raw, 8);
    const u32 oi = __builtin_nontemporal_load(oidx + i);
    float* dst = out + (size_t)oi * 32;

    #pragma unroll
    for (int half = 0; half < 2; ++half) {
        u32 q0x[8], q0y[8], q1x[8], q1y[8];
        float w0v[8], w1v[8];
        int edge[8];
        #pragma unroll
        for (int j = 0; j < 8; ++j) {
            const int l = half * 8 + j;
            const float rf = p.rf[l];
            const int ri = p.ri[l];
            const float px = xy.x * rf, py = xy.y * rf;
            const float fx = floorf(px), fy = floorf(py);
            w0v[j] = px - fx;
            w1v[j] = py - fy;
            const int tx = (int)fx, ty = (int)fy;
            const int cx0 = min(tx, ri);
            const int cy0 = min(ty, ri);
            const int cy1 = min(ty + 1, ri);
            edge[j] = (cx0 == ri);
            const u32* tab = dense + p.base[l];
            uint2 a, b;
            __builtin_memcpy(&a, tab + cy0 * p.stride[l] + cx0, 8);
            __builtin_memcpy(&b, tab + cy1 * p.stride[l] + cx0, 8);
            q0x[j] = a.x; q0y[j] = a.y; q1x[j] = b.x; q1y[j] = b.y;
        }
        float g[16];
        #pragma unroll
        for (int j = 0; j < 8; ++j) {
            const float w0 = w0v[j], w1 = w1v[j];
            const float u0 = 1.f - w0, u1 = 1.f - w1;
            const float2 e00 = h2f(q0x[j]);
            const float2 e01 = h2f(edge[j] ? q0x[j] : q0y[j]);
            const float2 e10 = h2f(q1x[j]);
            const float2 e11 = h2f(edge[j] ? q1x[j] : q1y[j]);
            g[j*2+0] = ((e00.x*u0 + e01.x*w0)*u1 + (e10.x*u0 + e11.x*w0)*w1) * FINV;
            g[j*2+1] = ((e00.y*u0 + e01.y*w0)*u1 + (e10.y*u0 + e11.y*w0)*w1) * FINV;
        }
        #pragma unroll
        for (int q = 0; q < 4; ++q) {
            f32x4 v; v.x = g[q*4+0]; v.y = g[q*4+1]; v.z = g[q*4+2]; v.w = g[q*4+3];
            __builtin_nontemporal_store(v, (f32x4*)(dst + half * 16 + q * 4));
        }
    }
}

// Mid-fallback (round-2 kernel): dense table + LDS transpose, unsorted points.
__global__ __launch_bounds__(256) void hash_embed_h(
    const float2* __restrict__ x,
    const u32*    __restrict__ dense,
    float*        __restrict__ out,
    Params p, int n)
{
    __shared__ float lds[8 * 512];
    const int tid = threadIdx.x;
    const int i = blockIdx.x * 256 + tid;
    float2 xy = make_float2(0.f, 0.f);
    if (i < n) {
        u64 raw = __builtin_nontemporal_load((const u64*)(x + i));
        __builtin_memcpy(&xy, &raw, 8);
    }
    const long long total = (long long)n * 32;
    const long long base  = (long long)blockIdx.x * 8192;

    #pragma unroll
    for (int half = 0; half < 2; ++half) {
        u32 q0x[8], q0y[8], q1x[8], q1y[8];
        float w0v[8], w1v[8];
        int edge[8];
        #pragma unroll
        for (int j = 0; j < 8; ++j) {
            const int l = half * 8 + j;
            const float rf = p.rf[l];
            const int ri = p.ri[l];
            const float px = xy.x * rf, py = xy.y * rf;
            const float fx = floorf(px), fy = floorf(py);
            w0v[j] = px - fx;
            w1v[j] = py - fy;
            const int tx = (int)fx, ty = (int)fy;
            const int cx0 = min(tx, ri);
            const int cy0 = min(ty, ri);
            const int cy1 = min(ty + 1, ri);
            edge[j] = (cx0 == ri);
            const u32* tab = dense + p.base[l];
            uint2 a, b;
            __builtin_memcpy(&a, tab + cy0 * p.stride[l] + cx0, 8);
            __builtin_memcpy(&b, tab + cy1 * p.stride[l] + cx0, 8);
            q0x[j] = a.x; q0y[j] = a.y; q1x[j] = b.x; q1y[j] = b.y;
        }
        if (half == 1) __syncthreads();
        #pragma unroll
        for (int j = 0; j < 8; ++j) {
            const float w0 = w0v[j], w1 = w1v[j];
            const float u0 = 1.f - w0, u1 = 1.f - w1;
            const float2 e00 = h2f(q0x[j]);
            const float2 e01 = h2f(edge[j] ? q0x[j] : q0y[j]);
            const float2 e10 = h2f(q1x[j]);
            const float2 e11 = h2f(edge[j] ? q1x[j] : q1y[j]);
            const float g0 = ((e00.x*u0 + e01.x*w0)*u1 + (e10.x*u0 + e11.x*w0)*w1) * FINV;
            const float g1 = ((e00.y*u0 + e01.y*w0)*u1 + (e10.y*u0 + e11.y*w0)*w1) * FINV;
            const int idx = j * 512 + ((2 * tid) ^ (j << 1));
            lds[idx]     = g0;
            lds[idx + 1] = g1;
        }
        __syncthreads();
        #pragma unroll
        for (int it = 0; it < 4; ++it) {
            const int f  = (it * 256 + tid) * 4;
            const int p2 = f >> 4;
            const int kk = f & 15;
            const int lh = kk >> 1;
            const long long gaddr = base + (long long)p2 * 32 + half * 16 + kk;
            if (gaddr < total) {
                const int s0 = lh * 512       + ((2 * p2) ^ (lh << 1));
                const int s1 = (lh + 1) * 512 + ((2 * p2) ^ ((lh + 1) << 1));
                f32x4 v;
                v.x = lds[s0]; v.y = lds[s0 + 1];
                v.z = lds[s1]; v.w = lds[s1 + 1];
                __builtin_nontemporal_store(v, (f32x4*)(out + gaddr));
            }
        }
    }
}

// Last fallback: direct f32 hash gathers, used only if ws is tiny.
__global__ __launch_bounds__(256) void hash_embed_direct(
    const float2* __restrict__ x,
    const float2* __restrict__ emb,
    float* __restrict__ out,
    Params p, int n)
{
    __shared__ float2 lds[NLVL * 256];
    const int tid = threadIdx.x;
    const int i = blockIdx.x * 256 + tid;
    float2 xy = make_float2(0.f, 0.f);
    if (i < n) xy = x[i];

    #pragma unroll
    for (int half = 0; half < 2; ++half) {
        float2 f[32];
        float w0v[8], w1v[8];
        #pragma unroll
        for (int j = 0; j < 8; ++j) {
            const int l = half * 8 + j;
            const float rf = p.rf[l];
            const int ri = p.ri[l];
            const float px = xy.x * rf, py = xy.y * rf;
            const float fx = floorf(px), fy = floorf(py);
            w0v[j] = px - fx;
            w1v[j] = py - fy;
            const int tx = (int)fx, ty = (int)fy;
            const unsigned cx0 = (unsigned)min(tx, ri);
            const unsigned cy0 = (unsigned)min(ty, ri);
            const unsigned cx1 = (unsigned)min(tx + 1, ri);
            const unsigned cy1 = (unsigned)min(ty + 1, ri);
            const unsigned hy0 = cy0 * PRIME1;
            const unsigned hy1 = cy1 * PRIME1;
            const float2* tab = emb + (size_t)l * TSIZE;
            f[j*4+0] = tab[(cx0 ^ hy0) & HMASK];
            f[j*4+1] = tab[(cx1 ^ hy0) & HMASK];
            f[j*4+2] = tab[(cx0 ^ hy1) & HMASK];
            f[j*4+3] = tab[(cx1 ^ hy1) & HMASK];
        }
        #pragma unroll
        for (int j = 0; j < 8; ++j) {
            const int l = half * 8 + j;
            const float w0 = w0v[j], w1 = w1v[j];
            const float u0 = 1.f - w0, u1 = 1.f - w1;
            const float2 f0 = f[j*4+0], f1 = f[j*4+1], f2 = f[j*4+2], f3 = f[j*4+3];
            const float g0 = (f0.x*u0 + f1.x*w0)*u1 + (f2.x*u0 + f3.x*w0)*w1;
            const float g1 = (f0.y*u0 + f1.y*w0)*u1 + (f2.y*u0 + f3.y*w0)*w1;
            lds[l * 256 + tid] = make_float2(g0, g1);
        }
    }
    __syncthreads();

    const float* lf = (const float*)lds;
    const long long total = (long long)n * 32;
    const long long base = (long long)blockIdx.x * 8192;
    #pragma unroll
    for (int it = 0; it < 8; ++it) {
        const int k = (it * 256 + tid) * 4;
        if (base + k < total) {
            const int p2 = k >> 5;
            const int l0 = (k & 31) >> 1;
            float4 v;
            v.x = lf[(l0 * 256 + p2) * 2 + 0];
            v.y = lf[(l0 * 256 + p2) * 2 + 1];
            v.z = lf[((l0 + 1) * 256 + p2) * 2 + 0];
            v.w = lf[((l0 + 1) * 256 + p2) * 2 + 1];
            *(float4*)(out + base + k) = v;
        }
    }
}

extern "C" void kernel_launch(void* const* d_in, const int* in_sizes, int n_in,
                              void* d_out, int out_size, void* d_ws, size_t ws_size,
                              hipStream_t stream) {
    const float2* x = (const float2*)d_in[0];
    const float2* emb = (const float2*)d_in[1];
    float* out = (float*)d_out;
    const int n = in_sizes[0] / 2;

    // numpy-exact per-level resolutions (ulp-sensitive floors at l=3,6,9,...)
    Params p;
    int off = 0;
    const double b = std::exp((std::log(512.0) - std::log(16.0)) / 15.0);
    for (int l = 0; l < NLVL; ++l) {
        const double r = std::floor(16.0 * std::pow(b, (double)l));
        p.rf[l] = (float)r;
        p.ri[l] = (int)r;
        p.stride[l] = p.ri[l] + 2;
        p.base[l] = off;
        off += (p.ri[l] + 1) * (p.ri[l] + 2);
    }
    const size_t D = (size_t)off;                    // dense cells (u32)
    const size_t need_dense = D * sizeof(u32);       // ~2.86 MiB

    // ws layout (u32 units): dense | counts | offs | cursor | oidx | sorted_x
    const size_t c_counts = D;
    const size_t c_offs   = c_counts + NBUCK;
    const size_t c_cursor = c_offs + NBUCK;
    const size_t c_oidx   = c_cursor + NBUCK;
    size_t c_sx           = c_oidx + (size_t)n;
    if (c_sx & 1) ++c_sx;                            // 8B-align float2 region
    const size_t need_sort = (c_sx + 2 * (size_t)n) * sizeof(u32);  // ~15.1 MiB

    const int grid = (n + 255) / 256;
    u32* base = (u32*)d_ws;

    if (ws_size >= need_sort) {
        u32* counts = base + c_counts;
        u32* offs   = base + c_offs;
        u32* cursor = base + c_cursor;
        u32* oidx   = base + c_oidx;
        float2* sx  = (float2*)(base + c_sx);
        hipMemsetAsync(counts, 0, NBUCK * sizeof(u32), stream);
        build_dense_h<<<dim3(513, 16), 256, 0, stream>>>(emb, base, p);
        hist_k<<<grid, 256, 0, stream>>>(x, counts, n);
        scan16k<<<1, 1024, 0, stream>>>(counts, offs, cursor);
        scatter_k<<<grid, 256, 0, stream>>>(x, cursor, sx, oidx, n);
        hash_embed_sorted<<<grid, 256, 0, stream>>>(sx, oidx, base, out, p, n);
    } else if (ws_size >= need_dense) {
        build_dense_h<<<dim3(513, 16), 256, 0, stream>>>(emb, base, p);
        hash_embed_h<<<grid, 256, 0, stream>>>(x, base, out, p, n);
    } else {
        hash_embed_direct<<<grid, 256, 0, stream>>>(x, emb, out, p, n);
    }
}

// Round 4
// 386.048 us; speedup vs baseline: 1.6483x; 1.6483x over previous
//
#include <hip/hip_runtime.h>
#include <hip/hip_fp16.h>
#include <cmath>

#define NLVL 16
#define TSIZE (1u << 19)
#define HMASK ((1u << 19) - 1u)
#define PRIME1 2654435761u
#define FSCALE 1024.0f          // 2^10: keeps |v|<=1e-4 in fp16-normal range
#define FINV   (1.0f/1024.0f)   // exact power of 2 -> no extra rounding
#define NBUCK_1D 64
#define NBUCK (NBUCK_1D * NBUCK_1D)   // 4096 buckets, ~244 pts each (~1 block)

typedef float f32x4 __attribute__((ext_vector_type(4)));
typedef unsigned int       u32;
typedef unsigned long long u64;

struct Params {
    float rf[NLVL];
    int   ri[NLVL];
    int   base[NLVL];     // u32 index of level's dense table inside ws
    int   stride[NLVL];   // ri+2 (one pad cell per row so the 8B load at cx=ri is in-bounds)
};

__device__ __forceinline__ float2 h2f(u32 u) {
    __half2 h; __builtin_memcpy(&h, &u, 4);
    return __half22float2(h);
}

__device__ __forceinline__ u32 part1by1(u32 v) {
    v &= 0xFF;
    v = (v | (v << 4)) & 0x0F0F;
    v = (v | (v << 2)) & 0x3333;
    v = (v | (v << 1)) & 0x5555;
    return v;
}

// Morton-ordered bucket id: consecutive buckets are spatially adjacent, so
// consecutive sorted blocks reuse the same table lines (L1/L2 locality).
__device__ __forceinline__ int bucket_of(float2 xy) {
    int bx = min(NBUCK_1D - 1, max(0, (int)(xy.x * (float)NBUCK_1D)));
    int by = min(NBUCK_1D - 1, max(0, (int)(xy.y * (float)NBUCK_1D)));
    return (int)(part1by1((u32)bx) | (part1by1((u32)by) << 1));
}

// Pre-pass: un-hash each level's window [0,res]^2 into a dense, L2-resident
// half2 table (scaled by 2^10). 714K cells -> 2.86 MiB.
__global__ __launch_bounds__(256) void build_dense_h(
    const float2* __restrict__ emb, u32* __restrict__ dense, Params p)
{
    const int l  = blockIdx.y;
    const int cy = blockIdx.x;
    const int ri = p.ri[l];
    if (cy > ri) return;
    const unsigned hy = (unsigned)cy * PRIME1;
    const u64* tab = (const u64*)(emb + (size_t)l * TSIZE);
    u32* drow = dense + p.base[l] + (size_t)cy * p.stride[l];
    for (int cx = threadIdx.x; cx <= ri; cx += 256) {
        u64 raw = __builtin_nontemporal_load(tab + (((unsigned)cx ^ hy) & HMASK));
        float2 v; __builtin_memcpy(&v, &raw, 8);
        const u32 h0 = (u32)__half_as_ushort(__float2half_rn(v.x * FSCALE));
        const u32 h1 = (u32)__half_as_ushort(__float2half_rn(v.y * FSCALE));
        drow[cx] = h0 | (h1 << 16);
    }
}

// Sort pass 1: bucket histogram (counts zeroed before launch).
__global__ __launch_bounds__(256) void hist_k(
    const float2* __restrict__ x, u32* __restrict__ counts, int n)
{
    const int i = blockIdx.x * 256 + threadIdx.x;
    if (i >= n) return;
    u64 raw = __builtin_nontemporal_load((const u64*)(x + i));
    float2 xy; __builtin_memcpy(&xy, &raw, 8);
    atomicAdd(&counts[bucket_of(xy)], 1u);
}

// Sort pass 2: exclusive prefix sum of 4096 counts, single 1024-thread block.
__global__ __launch_bounds__(1024) void scan4k(
    const u32* __restrict__ counts, u32* __restrict__ cursor)
{
    __shared__ u32 wsum[16];
    const int t = threadIdx.x;          // 0..1023, 4 counts each
    u32 v[4]; u32 s = 0;
    #pragma unroll
    for (int k = 0; k < 4; ++k) { v[k] = counts[t * 4 + k]; s += v[k]; }
    u32 inc = s;                        // wave-inclusive scan of thread sums
    #pragma unroll
    for (int d = 1; d < 64; d <<= 1) {
        u32 tt = __shfl_up(inc, d);
        if ((t & 63) >= d) inc += tt;
    }
    if ((t & 63) == 63) wsum[t >> 6] = inc;
    __syncthreads();
    if (t < 16) {                       // wave 0 scans the 16 wave sums
        u32 w = wsum[t];
        u32 wi = w;
        #pragma unroll
        for (int d = 1; d < 16; d <<= 1) {
            u32 tt = __shfl_up(wi, d);
            if (t >= d) wi += tt;
        }
        wsum[t] = wi - w;               // exclusive
    }
    __syncthreads();
    u32 run = wsum[t >> 6] + (inc - s); // this thread's exclusive prefix
    #pragma unroll
    for (int k = 0; k < 4; ++k) {
        cursor[t * 4 + k] = run;
        run += v[k];
    }
}

// Sort pass 3: scatter points into bucket-sorted order. Writes cluster in
// ~2.9 KB runs per bucket -> L2 merges them into full lines.
__global__ __launch_bounds__(256) void scatter_k(
    const float2* __restrict__ x, u32* __restrict__ cursor,
    float2* __restrict__ sx, u32* __restrict__ oidx, int n)
{
    const int i = blockIdx.x * 256 + threadIdx.x;
    if (i >= n) return;
    u64 raw = __builtin_nontemporal_load((const u64*)(x + i));
    float2 xy; __builtin_memcpy(&xy, &raw, 8);
    const u32 pos = atomicAdd(&cursor[bucket_of(xy)], 1u);
    sx[pos] = xy;
    oidx[pos] = (u32)i;
}

// Main (sorted): a wave's 64 points sit in ~one 1/64-square -> each level's
// row-gathers touch ~10 sectors instead of ~128. Each thread owns its point's
// full 32-float output line; NORMAL stores so L2 merges them into one
// fully-dirty 128B line per point (round-3's nt stores caused 2.7x write
// amplification via unmerged partial-sector HBM writes).
__global__ __launch_bounds__(256) void hash_embed_sorted(
    const float2* __restrict__ sx,
    const u32*    __restrict__ oidx,
    const u32*    __restrict__ dense,
    float*        __restrict__ out,
    Params p, int n)
{
    const int i = blockIdx.x * 256 + threadIdx.x;
    if (i >= n) return;
    u64 raw = __builtin_nontemporal_load((const u64*)(sx + i));
    float2 xy; __builtin_memcpy(&xy, &raw, 8);
    const u32 oi = __builtin_nontemporal_load(oidx + i);
    float* dst = out + (size_t)oi * 32;

    #pragma unroll
    for (int half = 0; half < 2; ++half) {
        u32 q0x[8], q0y[8], q1x[8], q1y[8];
        float w0v[8], w1v[8];
        int edge[8];
        #pragma unroll
        for (int j = 0; j < 8; ++j) {
            const int l = half * 8 + j;
            const float rf = p.rf[l];
            const int ri = p.ri[l];
            const float px = xy.x * rf, py = xy.y * rf;
            const float fx = floorf(px), fy = floorf(py);
            w0v[j] = px - fx;
            w1v[j] = py - fy;
            const int tx = (int)fx, ty = (int)fy;
            const int cx0 = min(tx, ri);
            const int cy0 = min(ty, ri);
            const int cy1 = min(ty + 1, ri);
            edge[j] = (cx0 == ri);
            const u32* tab = dense + p.base[l];
            uint2 a, b;
            __builtin_memcpy(&a, tab + cy0 * p.stride[l] + cx0, 8);
            __builtin_memcpy(&b, tab + cy1 * p.stride[l] + cx0, 8);
            q0x[j] = a.x; q0y[j] = a.y; q1x[j] = b.x; q1y[j] = b.y;
        }
        float g[16];
        #pragma unroll
        for (int j = 0; j < 8; ++j) {
            const float w0 = w0v[j], w1 = w1v[j];
            const float u0 = 1.f - w0, u1 = 1.f - w1;
            const float2 e00 = h2f(q0x[j]);
            const float2 e01 = h2f(edge[j] ? q0x[j] : q0y[j]);
            const float2 e10 = h2f(q1x[j]);
            const float2 e11 = h2f(edge[j] ? q1x[j] : q1y[j]);
            g[j*2+0] = ((e00.x*u0 + e01.x*w0)*u1 + (e10.x*u0 + e11.x*w0)*w1) * FINV;
            g[j*2+1] = ((e00.y*u0 + e01.y*w0)*u1 + (e10.y*u0 + e11.y*w0)*w1) * FINV;
        }
        #pragma unroll
        for (int q = 0; q < 4; ++q) {
            f32x4 v; v.x = g[q*4+0]; v.y = g[q*4+1]; v.z = g[q*4+2]; v.w = g[q*4+3];
            *(f32x4*)(dst + half * 16 + q * 4) = v;   // cached: L2 merges to full line
        }
    }
}

// Mid-fallback (round-2 kernel): dense table + LDS transpose, unsorted points.
__global__ __launch_bounds__(256) void hash_embed_h(
    const float2* __restrict__ x,
    const u32*    __restrict__ dense,
    float*        __restrict__ out,
    Params p, int n)
{
    __shared__ float lds[8 * 512];
    const int tid = threadIdx.x;
    const int i = blockIdx.x * 256 + tid;
    float2 xy = make_float2(0.f, 0.f);
    if (i < n) {
        u64 raw = __builtin_nontemporal_load((const u64*)(x + i));
        __builtin_memcpy(&xy, &raw, 8);
    }
    const long long total = (long long)n * 32;
    const long long base  = (long long)blockIdx.x * 8192;

    #pragma unroll
    for (int half = 0; half < 2; ++half) {
        u32 q0x[8], q0y[8], q1x[8], q1y[8];
        float w0v[8], w1v[8];
        int edge[8];
        #pragma unroll
        for (int j = 0; j < 8; ++j) {
            const int l = half * 8 + j;
            const float rf = p.rf[l];
            const int ri = p.ri[l];
            const float px = xy.x * rf, py = xy.y * rf;
            const float fx = floorf(px), fy = floorf(py);
            w0v[j] = px - fx;
            w1v[j] = py - fy;
            const int tx = (int)fx, ty = (int)fy;
            const int cx0 = min(tx, ri);
            const int cy0 = min(ty, ri);
            const int cy1 = min(ty + 1, ri);
            edge[j] = (cx0 == ri);
            const u32* tab = dense + p.base[l];
            uint2 a, b;
            __builtin_memcpy(&a, tab + cy0 * p.stride[l] + cx0, 8);
            __builtin_memcpy(&b, tab + cy1 * p.stride[l] + cx0, 8);
            q0x[j] = a.x; q0y[j] = a.y; q1x[j] = b.x; q1y[j] = b.y;
        }
        if (half == 1) __syncthreads();
        #pragma unroll
        for (int j = 0; j < 8; ++j) {
            const float w0 = w0v[j], w1 = w1v[j];
            const float u0 = 1.f - w0, u1 = 1.f - w1;
            const float2 e00 = h2f(q0x[j]);
            const float2 e01 = h2f(edge[j] ? q0x[j] : q0y[j]);
            const float2 e10 = h2f(q1x[j]);
            const float2 e11 = h2f(edge[j] ? q1x[j] : q1y[j]);
            const float g0 = ((e00.x*u0 + e01.x*w0)*u1 + (e10.x*u0 + e11.x*w0)*w1) * FINV;
            const float g1 = ((e00.y*u0 + e01.y*w0)*u1 + (e10.y*u0 + e11.y*w0)*w1) * FINV;
            const int idx = j * 512 + ((2 * tid) ^ (j << 1));
            lds[idx]     = g0;
            lds[idx + 1] = g1;
        }
        __syncthreads();
        #pragma unroll
        for (int it = 0; it < 4; ++it) {
            const int f  = (it * 256 + tid) * 4;
            const int p2 = f >> 4;
            const int kk = f & 15;
            const int lh = kk >> 1;
            const long long gaddr = base + (long long)p2 * 32 + half * 16 + kk;
            if (gaddr < total) {
                const int s0 = lh * 512       + ((2 * p2) ^ (lh << 1));
                const int s1 = (lh + 1) * 512 + ((2 * p2) ^ ((lh + 1) << 1));
                f32x4 v;
                v.x = lds[s0]; v.y = lds[s0 + 1];
                v.z = lds[s1]; v.w = lds[s1 + 1];
                __builtin_nontemporal_store(v, (f32x4*)(out + gaddr));
            }
        }
    }
}

// Last fallback: direct f32 hash gathers, used only if ws is tiny.
__global__ __launch_bounds__(256) void hash_embed_direct(
    const float2* __restrict__ x,
    const float2* __restrict__ emb,
    float* __restrict__ out,
    Params p, int n)
{
    __shared__ float2 lds[NLVL * 256];
    const int tid = threadIdx.x;
    const int i = blockIdx.x * 256 + tid;
    float2 xy = make_float2(0.f, 0.f);
    if (i < n) xy = x[i];

    #pragma unroll
    for (int half = 0; half < 2; ++half) {
        float2 f[32];
        float w0v[8], w1v[8];
        #pragma unroll
        for (int j = 0; j < 8; ++j) {
            const int l = half * 8 + j;
            const float rf = p.rf[l];
            const int ri = p.ri[l];
            const float px = xy.x * rf, py = xy.y * rf;
            const float fx = floorf(px), fy = floorf(py);
            w0v[j] = px - fx;
            w1v[j] = py - fy;
            const int tx = (int)fx, ty = (int)fy;
            const unsigned cx0 = (unsigned)min(tx, ri);
            const unsigned cy0 = (unsigned)min(ty, ri);
            const unsigned cx1 = (unsigned)min(tx + 1, ri);
            const unsigned cy1 = (unsigned)min(ty + 1, ri);
            const unsigned hy0 = cy0 * PRIME1;
            const unsigned hy1 = cy1 * PRIME1;
            const float2* tab = emb + (size_t)l * TSIZE;
            f[j*4+0] = tab[(cx0 ^ hy0) & HMASK];
            f[j*4+1] = tab[(cx1 ^ hy0) & HMASK];
            f[j*4+2] = tab[(cx0 ^ hy1) & HMASK];
            f[j*4+3] = tab[(cx1 ^ hy1) & HMASK];
        }
        #pragma unroll
        for (int j = 0; j < 8; ++j) {
            const int l = half * 8 + j;
            const float w0 = w0v[j], w1 = w1v[j];
            const float u0 = 1.f - w0, u1 = 1.f - w1;
            const float2 f0 = f[j*4+0], f1 = f[j*4+1], f2 = f[j*4+2], f3 = f[j*4+3];
            const float g0 = (f0.x*u0 + f1.x*w0)*u1 + (f2.x*u0 + f3.x*w0)*w1;
            const float g1 = (f0.y*u0 + f1.y*w0)*u1 + (f2.y*u0 + f3.y*w0)*w1;
            lds[l * 256 + tid] = make_float2(g0, g1);
        }
    }
    __syncthreads();

    const float* lf = (const float*)lds;
    const long long total = (long long)n * 32;
    const long long base = (long long)blockIdx.x * 8192;
    #pragma unroll
    for (int it = 0; it < 8; ++it) {
        const int k = (it * 256 + tid) * 4;
        if (base + k < total) {
            const int p2 = k >> 5;
            const int l0 = (k & 31) >> 1;
            float4 v;
            v.x = lf[(l0 * 256 + p2) * 2 + 0];
            v.y = lf[(l0 * 256 + p2) * 2 + 1];
            v.z = lf[((l0 + 1) * 256 + p2) * 2 + 0];
            v.w = lf[((l0 + 1) * 256 + p2) * 2 + 1];
            *(float4*)(out + base + k) = v;
        }
    }
}

extern "C" void kernel_launch(void* const* d_in, const int* in_sizes, int n_in,
                              void* d_out, int out_size, void* d_ws, size_t ws_size,
                              hipStream_t stream) {
    const float2* x = (const float2*)d_in[0];
    const float2* emb = (const float2*)d_in[1];
    float* out = (float*)d_out;
    const int n = in_sizes[0] / 2;

    // numpy-exact per-level resolutions (ulp-sensitive floors at l=3,6,9,...)
    Params p;
    int off = 0;
    const double b = std::exp((std::log(512.0) - std::log(16.0)) / 15.0);
    for (int l = 0; l < NLVL; ++l) {
        const double r = std::floor(16.0 * std::pow(b, (double)l));
        p.rf[l] = (float)r;
        p.ri[l] = (int)r;
        p.stride[l] = p.ri[l] + 2;
        p.base[l] = off;
        off += (p.ri[l] + 1) * (p.ri[l] + 2);
    }
    const size_t D = (size_t)off;                    // dense cells (u32)
    const size_t need_dense = D * sizeof(u32);       // ~2.86 MiB

    // ws layout (u32 units): dense | counts | cursor | oidx | sorted_x
    const size_t c_counts = D;
    const size_t c_cursor = c_counts + NBUCK;
    const size_t c_oidx   = c_cursor + NBUCK;
    size_t c_sx           = c_oidx + (size_t)n;
    if (c_sx & 1) ++c_sx;                            // 8B-align float2 region
    const size_t need_sort = (c_sx + 2 * (size_t)n) * sizeof(u32);  // ~15 MiB

    const int grid = (n + 255) / 256;
    u32* base = (u32*)d_ws;

    if (ws_size >= need_sort) {
        u32* counts = base + c_counts;
        u32* cursor = base + c_cursor;
        u32* oidx   = base + c_oidx;
        float2* sx  = (float2*)(base + c_sx);
        hipMemsetAsync(counts, 0, NBUCK * sizeof(u32), stream);
        build_dense_h<<<dim3(513, 16), 256, 0, stream>>>(emb, base, p);
        hist_k<<<grid, 256, 0, stream>>>(x, counts, n);
        scan4k<<<1, 1024, 0, stream>>>(counts, cursor);
        scatter_k<<<grid, 256, 0, stream>>>(x, cursor, sx, oidx, n);
        hash_embed_sorted<<<grid, 256, 0, stream>>>(sx, oidx, base, out, p, n);
    } else if (ws_size >= need_dense) {
        build_dense_h<<<dim3(513, 16), 256, 0, stream>>>(emb, base, p);
        hash_embed_h<<<grid, 256, 0, stream>>>(x, base, out, p, n);
    } else {
        hash_embed_direct<<<grid, 256, 0, stream>>>(x, emb, out, p, n);
    }
}

// Round 5
// 293.382 us; speedup vs baseline: 2.1690x; 1.3159x over previous
//
#include <hip/hip_runtime.h>
#include <hip/hip_fp16.h>
#include <cmath>

#define NLVL 16
#define TSIZE (1u << 19)
#define HMASK ((1u << 19) - 1u)
#define PRIME1 2654435761u
#define FSCALE 1024.0f          // 2^10: keeps |v|<=1e-4 in fp16-normal range
#define FINV   (1.0f/1024.0f)   // exact power of 2 -> no extra rounding

typedef float f32x4 __attribute__((ext_vector_type(4)));
typedef unsigned int       u32;
typedef unsigned long long u64;

struct Params {
    float rf[NLVL];
    int   ri[NLVL];
    int   base[NLVL];     // u32 index of level's dense table inside ws
    int   stride[NLVL];   // ri+2 (one pad cell per row so the 8B load at cx=ri is in-bounds)
};

__device__ __forceinline__ float2 h2f(u32 u) {
    __half2 h; __builtin_memcpy(&h, &u, 4);
    return __half22float2(h);
}

// Pre-pass: un-hash each level's window [0,res]^2 into a dense, L2-resident
// half2 table (scaled by 2^10). 714K cells -> 2.86 MiB (fits 4 MiB/XCD L2).
// (cx ^ (cy*PRIME1)) & MASK is a lane-permutation of an aligned contiguous
// window for 64 consecutive cx -> loads are coalesced.
__global__ __launch_bounds__(256) void build_dense_h(
    const float2* __restrict__ emb, u32* __restrict__ dense, Params p)
{
    const int l  = blockIdx.y;
    const int cy = blockIdx.x;
    const int ri = p.ri[l];
    if (cy > ri) return;
    const unsigned hy = (unsigned)cy * PRIME1;
    const u64* tab = (const u64*)(emb + (size_t)l * TSIZE);
    u32* drow = dense + p.base[l] + (size_t)cy * p.stride[l];
    for (int cx = threadIdx.x; cx <= ri; cx += 256) {
        u64 raw = __builtin_nontemporal_load(tab + (((unsigned)cx ^ hy) & HMASK));
        float2 v; __builtin_memcpy(&v, &raw, 8);
        const u32 h0 = (u32)__half_as_ushort(__float2half_rn(v.x * FSCALE));
        const u32 h1 = (u32)__half_as_ushort(__float2half_rn(v.y * FSCALE));
        drow[cx] = h0 | (h1 << 16);
    }
}

// Main: barrier-free, zero-LDS. Thread i owns point i and its full 128B
// output line out[i*32..i*32+32). All 32 row-pair gathers (16 levels) issue
// up front for max memory-level parallelism; L2-resident table serves them.
// Stores are CACHED (not nt): a wave's 8 strided dwordx4 stores fully cover
// 64 consecutive 128B lines, which L2 merges into fully-dirty evictions
// (nt 16B/line stores caused 2.7x write amplification in round 3).
__global__ __launch_bounds__(256) void hash_embed_flat(
    const float2* __restrict__ x,
    const u32*    __restrict__ dense,
    float*        __restrict__ out,
    Params p, int n)
{
    const int i = blockIdx.x * 256 + threadIdx.x;
    if (i >= n) return;
    u64 raw = __builtin_nontemporal_load((const u64*)(x + i));
    float2 xy; __builtin_memcpy(&xy, &raw, 8);
    float* dst = out + (size_t)i * 32;

    u32 q0x[NLVL], q0y[NLVL], q1x[NLVL], q1y[NLVL];
    float w0v[NLVL], w1v[NLVL];
    int edge[NLVL];

    // phase 1: all 32 gathers in flight
    #pragma unroll
    for (int l = 0; l < NLVL; ++l) {
        const float rf = p.rf[l];
        const int ri = p.ri[l];
        const float px = xy.x * rf, py = xy.y * rf;
        const float fx = floorf(px), fy = floorf(py);
        w0v[l] = px - fx;
        w1v[l] = py - fy;
        const int tx = (int)fx, ty = (int)fy;
        const int cx0 = min(tx, ri);
        const int cy0 = min(ty, ri);
        const int cy1 = min(ty + 1, ri);
        edge[l] = (cx0 == ri);                 // then cx1==cx0 (clip)
        const u32* tab = dense + p.base[l];
        uint2 a, b;
        __builtin_memcpy(&a, tab + cy0 * p.stride[l] + cx0, 8);
        __builtin_memcpy(&b, tab + cy1 * p.stride[l] + cx0, 8);
        q0x[l] = a.x; q0y[l] = a.y; q1x[l] = b.x; q1y[l] = b.y;
    }

    // phase 2: blend (reference fp32 order) + direct line store
    #pragma unroll
    for (int half = 0; half < 2; ++half) {
        float g[16];
        #pragma unroll
        for (int j = 0; j < 8; ++j) {
            const int l = half * 8 + j;
            const float w0 = w0v[l], w1 = w1v[l];
            const float u0 = 1.f - w0, u1 = 1.f - w1;
            const float2 e00 = h2f(q0x[l]);
            const float2 e01 = h2f(edge[l] ? q0x[l] : q0y[l]);
            const float2 e10 = h2f(q1x[l]);
            const float2 e11 = h2f(edge[l] ? q1x[l] : q1y[l]);
            g[j*2+0] = ((e00.x*u0 + e01.x*w0)*u1 + (e10.x*u0 + e11.x*w0)*w1) * FINV;
            g[j*2+1] = ((e00.y*u0 + e01.y*w0)*u1 + (e10.y*u0 + e11.y*w0)*w1) * FINV;
        }
        #pragma unroll
        for (int q = 0; q < 4; ++q) {
            f32x4 v; v.x = g[q*4+0]; v.y = g[q*4+1]; v.z = g[q*4+2]; v.w = g[q*4+3];
            *(f32x4*)(dst + half * 16 + q * 4) = v;   // cached: L2 merges to full lines
        }
    }
}

// Fallback: direct f32 hash gathers, used only if ws is too small.
__global__ __launch_bounds__(256) void hash_embed_direct(
    const float2* __restrict__ x,
    const float2* __restrict__ emb,
    float* __restrict__ out,
    Params p, int n)
{
    __shared__ float2 lds[NLVL * 256];
    const int tid = threadIdx.x;
    const int i = blockIdx.x * 256 + tid;
    float2 xy = make_float2(0.f, 0.f);
    if (i < n) xy = x[i];

    #pragma unroll
    for (int half = 0; half < 2; ++half) {
        float2 f[32];
        float w0v[8], w1v[8];
        #pragma unroll
        for (int j = 0; j < 8; ++j) {
            const int l = half * 8 + j;
            const float rf = p.rf[l];
            const int ri = p.ri[l];
            const float px = xy.x * rf, py = xy.y * rf;
            const float fx = floorf(px), fy = floorf(py);
            w0v[j] = px - fx;
            w1v[j] = py - fy;
            const int tx = (int)fx, ty = (int)fy;
            const unsigned cx0 = (unsigned)min(tx, ri);
            const unsigned cy0 = (unsigned)min(ty, ri);
            const unsigned cx1 = (unsigned)min(tx + 1, ri);
            const unsigned cy1 = (unsigned)min(ty + 1, ri);
            const unsigned hy0 = cy0 * PRIME1;
            const unsigned hy1 = cy1 * PRIME1;
            const float2* tab = emb + (size_t)l * TSIZE;
            f[j*4+0] = tab[(cx0 ^ hy0) & HMASK];
            f[j*4+1] = tab[(cx1 ^ hy0) & HMASK];
            f[j*4+2] = tab[(cx0 ^ hy1) & HMASK];
            f[j*4+3] = tab[(cx1 ^ hy1) & HMASK];
        }
        #pragma unroll
        for (int j = 0; j < 8; ++j) {
            const int l = half * 8 + j;
            const float w0 = w0v[j], w1 = w1v[j];
            const float u0 = 1.f - w0, u1 = 1.f - w1;
            const float2 f0 = f[j*4+0], f1 = f[j*4+1], f2 = f[j*4+2], f3 = f[j*4+3];
            const float g0 = (f0.x*u0 + f1.x*w0)*u1 + (f2.x*u0 + f3.x*w0)*w1;
            const float g1 = (f0.y*u0 + f1.y*w0)*u1 + (f2.y*u0 + f3.y*w0)*w1;
            lds[l * 256 + tid] = make_float2(g0, g1);
        }
    }
    __syncthreads();

    const float* lf = (const float*)lds;
    const long long total = (long long)n * 32;
    const long long base = (long long)blockIdx.x * 8192;
    #pragma unroll
    for (int it = 0; it < 8; ++it) {
        const int k = (it * 256 + tid) * 4;
        if (base + k < total) {
            const int p2 = k >> 5;
            const int l0 = (k & 31) >> 1;
            float4 v;
            v.x = lf[(l0 * 256 + p2) * 2 + 0];
            v.y = lf[(l0 * 256 + p2) * 2 + 1];
            v.z = lf[((l0 + 1) * 256 + p2) * 2 + 0];
            v.w = lf[((l0 + 1) * 256 + p2) * 2 + 1];
            *(float4*)(out + base + k) = v;
        }
    }
}

extern "C" void kernel_launch(void* const* d_in, const int* in_sizes, int n_in,
                              void* d_out, int out_size, void* d_ws, size_t ws_size,
                              hipStream_t stream) {
    const float2* x = (const float2*)d_in[0];
    const float2* emb = (const float2*)d_in[1];
    float* out = (float*)d_out;
    const int n = in_sizes[0] / 2;

    // numpy-exact per-level resolutions (ulp-sensitive floors at l=3,6,9,...)
    Params p;
    int off = 0;
    const double b = std::exp((std::log(512.0) - std::log(16.0)) / 15.0);
    for (int l = 0; l < NLVL; ++l) {
        const double r = std::floor(16.0 * std::pow(b, (double)l));
        p.rf[l] = (float)r;
        p.ri[l] = (int)r;
        p.stride[l] = p.ri[l] + 2;
        p.base[l] = off;
        off += (p.ri[l] + 1) * (p.ri[l] + 2);
    }
    const size_t need = (size_t)off * sizeof(u32);   // ~2.86 MiB

    const int grid = (n + 255) / 256;
    if (ws_size >= need) {
        build_dense_h<<<dim3(513, 16), 256, 0, stream>>>(emb, (u32*)d_ws, p);
        hash_embed_flat<<<grid, 256, 0, stream>>>(x, (const u32*)d_ws, out, p, n);
    } else {
        hash_embed_direct<<<grid, 256, 0, stream>>>(x, emb, out, p, n);
    }
}

// Round 6
// 231.213 us; speedup vs baseline: 2.7522x; 1.2689x over previous
//
#include <hip/hip_runtime.h>
#include <hip/hip_fp16.h>
#include <cmath>

#define NLVL 16
#define TSIZE (1u << 19)
#define HMASK ((1u << 19) - 1u)
#define PRIME1 2654435761u
#define FSCALE 1024.0f          // 2^10: keeps |v|<=1e-4 in fp16-normal range
#define FINV   (1.0f/1024.0f)   // exact power of 2 -> no extra rounding

typedef float f32x4 __attribute__((ext_vector_type(4)));
typedef unsigned int       u32;
typedef unsigned long long u64;

struct Params {
    float rf[NLVL];
    int   ri[NLVL];
    int   base[NLVL];     // uint2-entry index of level's table inside ws
    int   stride[NLVL];   // ri+2 entries/row (pad entry so 16B load at cx0=ri is in-bounds)
};

__device__ __forceinline__ float2 h2f(u32 u) {
    __half2 h; __builtin_memcpy(&h, &u, 4);
    return __half22float2(h);
}

// Pre-pass: un-hash into a ROW-PAIR DUPLICATED dense table.
// entry(l, r, cx) = { cell(cx, r), cell(cx, min(r+1, ri)) }  (8B, fp16x2 each)
// -> a full bilinear quad is ONE 16B load (entries cx0, cx0+1):
//    q.x = e00(cx0,r)   q.y = e10(cx0,r+1)   q.z = e01(cx1,r)   q.w = e11(cx1,r+1)
// Halves the L2 lines per gather (1 instead of 2 rows). ~5.7 MiB total:
// spills one XCD L2 partially; L3 (256MB) absorbs, FETCH_SIZE stays low.
__global__ __launch_bounds__(256) void build_dense_q(
    const float2* __restrict__ emb, uint2* __restrict__ dense, Params p)
{
    const int l  = blockIdx.y;
    const int r  = blockIdx.x;
    const int ri = p.ri[l];
    if (r > ri) return;
    const unsigned hy0 = (unsigned)r * PRIME1;
    const unsigned hy1 = (unsigned)min(r + 1, ri) * PRIME1;
    const u64* tab = (const u64*)(emb + (size_t)l * TSIZE);
    uint2* drow = dense + p.base[l] + (size_t)r * p.stride[l];
    for (int cx = threadIdx.x; cx <= ri; cx += 256) {
        // NT loads: emb is read-once(-ish), keep it out of L2
        u64 raw0 = __builtin_nontemporal_load(tab + (((unsigned)cx ^ hy0) & HMASK));
        u64 raw1 = __builtin_nontemporal_load(tab + (((unsigned)cx ^ hy1) & HMASK));
        float2 v0, v1;
        __builtin_memcpy(&v0, &raw0, 8);
        __builtin_memcpy(&v1, &raw1, 8);
        uint2 e;
        e.x = (u32)__half_as_ushort(__float2half_rn(v0.x * FSCALE))
            | ((u32)__half_as_ushort(__float2half_rn(v0.y * FSCALE)) << 16);
        e.y = (u32)__half_as_ushort(__float2half_rn(v1.x * FSCALE))
            | ((u32)__half_as_ushort(__float2half_rn(v1.y * FSCALE)) << 16);
        drow[cx] = e;
    }
}

// Main: ONE 16B quad-load per level (16 L2 lines/point instead of 32), all 16
// issued up front for max MLP (sched_barrier pins issue-all-then-consume).
// Write path = round-2's proven LDS transpose + nt coalesced stores
// (compulsory 132MB writes; per-thread cached line stores cost +77MB RFO in r5).
__global__ __launch_bounds__(256) void hash_embed_q(
    const float2* __restrict__ x,
    const uint2*  __restrict__ dense,
    float*        __restrict__ out,
    Params p, int n)
{
    __shared__ float lds[8 * 512];   // 16 KiB, XOR-swizzled
    const int tid = threadIdx.x;
    const int i = blockIdx.x * 256 + tid;
    float2 xy = make_float2(0.f, 0.f);
    if (i < n) {
        u64 raw = __builtin_nontemporal_load((const u64*)(x + i));
        __builtin_memcpy(&xy, &raw, 8);
    }

    uint4 q[NLVL];
    float w0v[NLVL], w1v[NLVL];
    u32 edgemask = 0;

    // phase 1: all 16 quad gathers in flight
    #pragma unroll
    for (int l = 0; l < NLVL; ++l) {
        const float rf = p.rf[l];
        const int ri = p.ri[l];
        const float px = xy.x * rf, py = xy.y * rf;
        const float fx = floorf(px), fy = floorf(py);
        w0v[l] = px - fx;
        w1v[l] = py - fy;
        const int tx = (int)fx, ty = (int)fy;
        const int cx0 = min(tx, ri);
        const int cy0 = min(ty, ri);
        edgemask |= (u32)(cx0 == ri) << l;     // then cx1==cx0 (clip)
        const uint2* a = dense + p.base[l] + cy0 * p.stride[l] + cx0;
        __builtin_memcpy(&q[l], a, 16);        // 8B-aligned dwordx4
    }
    __builtin_amdgcn_sched_barrier(0);         // don't sink loads into blends

    const long long total = (long long)n * 32;
    const long long base  = (long long)blockIdx.x * 8192;

    #pragma unroll
    for (int half = 0; half < 2; ++half) {
        if (half == 1) __syncthreads();        // half-0 readers done before overwrite
        #pragma unroll
        for (int j = 0; j < 8; ++j) {
            const int l = half * 8 + j;
            const float w0 = w0v[l], w1 = w1v[l];
            const float u0 = 1.f - w0, u1 = 1.f - w1;
            const bool ed = (edgemask >> l) & 1u;
            const float2 e00 = h2f(q[l].x);
            const float2 e10 = h2f(q[l].y);
            const float2 e01 = h2f(ed ? q[l].x : q[l].z);
            const float2 e11 = h2f(ed ? q[l].y : q[l].w);
            const float g0 = ((e00.x*u0 + e01.x*w0)*u1 + (e10.x*u0 + e11.x*w0)*w1) * FINV;
            const float g1 = ((e00.y*u0 + e01.y*w0)*u1 + (e10.y*u0 + e11.y*w0)*w1) * FINV;
            const int idx = j * 512 + ((2 * tid) ^ (j << 1));  // bank swizzle
            lds[idx]     = g0;
            lds[idx + 1] = g1;
        }
        __syncthreads();

        // coalesced nt write-out of this half (levels [half*8, half*8+8) are a
        // contiguous, 64B-aligned 16-float chunk per point)
        #pragma unroll
        for (int it = 0; it < 4; ++it) {
            const int f  = (it * 256 + tid) * 4;   // 0..4095
            const int p2 = f >> 4;                 // point within block
            const int kk = f & 15;                 // float within 16-float half
            const int lh = kk >> 1;                // {0,2,4,6}
            const long long g = base + (long long)p2 * 32 + half * 16 + kk;
            if (g < total) {
                const int s0 = lh * 512       + ((2 * p2) ^ (lh << 1));
                const int s1 = (lh + 1) * 512 + ((2 * p2) ^ ((lh + 1) << 1));
                f32x4 v;
                v.x = lds[s0]; v.y = lds[s0 + 1];
                v.z = lds[s1]; v.w = lds[s1 + 1];
                __builtin_nontemporal_store(v, (f32x4*)(out + g));
            }
        }
    }
}

// Fallback: direct f32 hash gathers, used only if ws is too small.
__global__ __launch_bounds__(256) void hash_embed_direct(
    const float2* __restrict__ x,
    const float2* __restrict__ emb,
    float* __restrict__ out,
    Params p, int n)
{
    __shared__ float2 lds[NLVL * 256];
    const int tid = threadIdx.x;
    const int i = blockIdx.x * 256 + tid;
    float2 xy = make_float2(0.f, 0.f);
    if (i < n) xy = x[i];

    #pragma unroll
    for (int half = 0; half < 2; ++half) {
        float2 f[32];
        float w0v[8], w1v[8];
        #pragma unroll
        for (int j = 0; j < 8; ++j) {
            const int l = half * 8 + j;
            const float rf = p.rf[l];
            const int ri = p.ri[l];
            const float px = xy.x * rf, py = xy.y * rf;
            const float fx = floorf(px), fy = floorf(py);
            w0v[j] = px - fx;
            w1v[j] = py - fy;
            const int tx = (int)fx, ty = (int)fy;
            const unsigned cx0 = (unsigned)min(tx, ri);
            const unsigned cy0 = (unsigned)min(ty, ri);
            const unsigned cx1 = (unsigned)min(tx + 1, ri);
            const unsigned cy1 = (unsigned)min(ty + 1, ri);
            const unsigned hy0 = cy0 * PRIME1;
            const unsigned hy1 = cy1 * PRIME1;
            const float2* tab = emb + (size_t)l * TSIZE;
            f[j*4+0] = tab[(cx0 ^ hy0) & HMASK];
            f[j*4+1] = tab[(cx1 ^ hy0) & HMASK];
            f[j*4+2] = tab[(cx0 ^ hy1) & HMASK];
            f[j*4+3] = tab[(cx1 ^ hy1) & HMASK];
        }
        #pragma unroll
        for (int j = 0; j < 8; ++j) {
            const int l = half * 8 + j;
            const float w0 = w0v[j], w1 = w1v[j];
            const float u0 = 1.f - w0, u1 = 1.f - w1;
            const float2 f0 = f[j*4+0], f1 = f[j*4+1], f2 = f[j*4+2], f3 = f[j*4+3];
            const float g0 = (f0.x*u0 + f1.x*w0)*u1 + (f2.x*u0 + f3.x*w0)*w1;
            const float g1 = (f0.y*u0 + f1.y*w0)*u1 + (f2.y*u0 + f3.y*w0)*w1;
            lds[l * 256 + tid] = make_float2(g0, g1);
        }
    }
    __syncthreads();

    const float* lf = (const float*)lds;
    const long long total = (long long)n * 32;
    const long long base = (long long)blockIdx.x * 8192;
    #pragma unroll
    for (int it = 0; it < 8; ++it) {
        const int k = (it * 256 + tid) * 4;
        if (base + k < total) {
            const int p2 = k >> 5;
            const int l0 = (k & 31) >> 1;
            float4 v;
            v.x = lf[(l0 * 256 + p2) * 2 + 0];
            v.y = lf[(l0 * 256 + p2) * 2 + 1];
            v.z = lf[((l0 + 1) * 256 + p2) * 2 + 0];
            v.w = lf[((l0 + 1) * 256 + p2) * 2 + 1];
            *(float4*)(out + base + k) = v;
        }
    }
}

extern "C" void kernel_launch(void* const* d_in, const int* in_sizes, int n_in,
                              void* d_out, int out_size, void* d_ws, size_t ws_size,
                              hipStream_t stream) {
    const float2* x = (const float2*)d_in[0];
    const float2* emb = (const float2*)d_in[1];
    float* out = (float*)d_out;
    const int n = in_sizes[0] / 2;

    // numpy-exact per-level resolutions (ulp-sensitive floors at l=3,6,9,...)
    Params p;
    int off = 0;
    const double b = std::exp((std::log(512.0) - std::log(16.0)) / 15.0);
    for (int l = 0; l < NLVL; ++l) {
        const double r = std::floor(16.0 * std::pow(b, (double)l));
        p.rf[l] = (float)r;
        p.ri[l] = (int)r;
        p.stride[l] = p.ri[l] + 2;
        p.base[l] = off;
        off += (p.ri[l] + 1) * (p.ri[l] + 2);
    }
    const size_t need = (size_t)off * sizeof(uint2);   // ~5.7 MiB (row-pair dup)

    const int grid = (n + 255) / 256;
    if (ws_size >= need) {
        build_dense_q<<<dim3(513, 16), 256, 0, stream>>>(emb, (uint2*)d_ws, p);
        hash_embed_q<<<grid, 256, 0, stream>>>(x, (const uint2*)d_ws, out, p, n);
    } else {
        hash_embed_direct<<<grid, 256, 0, stream>>>(x, emb, out, p, n);
    }
}